// Round 13
// baseline (125.823 us; speedup 1.0000x reference)
//
#include <hip/hip_runtime.h>

#define CIN   256
#define COUT  256
#define HH    64
#define WW    64
#define KD    2304         // CIN * 9
#define NPIX  16384        // B * HO * WO
#define SPLIT 16
#define CPS   (CIN / SPLIT)
#define NSTEP 36           // K per half = 1152 = 36 x 32

typedef __attribute__((ext_vector_type(4))) float  float4v;
typedef __attribute__((ext_vector_type(4))) unsigned int uint4v;
typedef _Float16 h2 __attribute__((ext_vector_type(2)));
typedef _Float16 h8 __attribute__((ext_vector_type(8)));
typedef unsigned int u32;
typedef unsigned short u16;

__device__ __forceinline__ h2 as_h2(u32 v) { union { u32 u; h2 h; } x; x.u = v; return x.h; }
__device__ __forceinline__ u32 as_u32(h2 h) { union { u32 u; h2 h; } x; x.h = h; return x.u; }
__device__ __forceinline__ u16 f2h_bits(float f) { _Float16 h = (_Float16)f; return *(u16*)&h; }

__device__ __forceinline__ void gload_lds16(const void* g, void* l) {
  __builtin_amdgcn_global_load_lds((const __attribute__((address_space(1))) u32*)g,
                                   (__attribute__((address_space(3))) u32*)l, 16, 0, 0);
}

// ---------------- Kernel 1a: offset/mask partials, channel-split x16 ----------------
__global__ __launch_bounds__(256) void offmask_part_kernel(
    const float* __restrict__ x,
    const float* __restrict__ off_dw, const float* __restrict__ off_pw,
    const float* __restrict__ mask_dw, const float* __restrict__ mask_pw,
    float* __restrict__ part)
{
  int m = blockIdx.x * 256 + threadIdx.x;   // pixel id: b*4096 + ho*64 + wo
  int s = blockIdx.y;                        // channel split 0..SPLIT-1
  int b = m >> 12, pix = m & 4095;
  int ho = pix >> 6, wo = pix & 63;
  const float* xb = x + (size_t)b * CIN * 4096;

  float acc[27];
#pragma unroll
  for (int j = 0; j < 27; ++j) acc[j] = 0.f;

  int c0 = s * CPS;
  for (int ci = 0; ci < CPS; ++ci) {
    int c = c0 + ci;
    const float* xc = xb + (size_t)c * 4096;
    float d_off = 0.f, d_msk = 0.f;
#pragma unroll
    for (int t = 0; t < 9; ++t) {
      int gy = ho + t / 3 - 1, gx = wo + t % 3 - 1;
      bool ok = (gy >= 0) & (gy < HH) & (gx >= 0) & (gx < WW);
      float v = ok ? xc[gy * 64 + gx] : 0.f;
      d_off += v * off_dw[c * 9 + t];
      d_msk += v * mask_dw[c * 9 + t];
    }
#pragma unroll
    for (int j = 0; j < 18; ++j) acc[j] += d_off * off_pw[j * 256 + c];
#pragma unroll
    for (int j = 0; j < 9; ++j) acc[18 + j] += d_msk * mask_pw[j * 256 + c];
  }
  float* pp = part + ((size_t)s * NPIX + m) * 32;
#pragma unroll
  for (int j = 0; j < 27; ++j) pp[j] = acc[j];
}

// ---------------- Kernel 1b: reduce partials -> rec (sigmoid on mask) ----------------
__global__ __launch_bounds__(256) void offmask_reduce_kernel(
    const float* __restrict__ part, float* __restrict__ rec)
{
  int i = blockIdx.x * 256 + threadIdx.x;   // over NPIX*32
  int m = i >> 5, j = i & 31;
  if (j >= 27) { rec[i] = 0.f; return; }
  float sum = 0.f;
#pragma unroll
  for (int s = 0; s < SPLIT; ++s) sum += part[((size_t)s * NPIX + m) * 32 + j];
  rec[i] = (j < 18) ? sum : 2.f / (1.f + __expf(-sum));
}

// ---------------- Kernel 2: weight f32 (co,c,ki,kj) -> f16 [co][kk*256 + c] ----------------
__global__ __launch_bounds__(256) void wconv_kernel(const float* __restrict__ w,
                                                    u16* __restrict__ wb)
{
  int i = blockIdx.x * 256 + threadIdx.x;     // over COUT*KD
  int co = i / KD, rem = i - co * KD;
  int c = rem / 9, kk = rem - c * 9;
  wb[co * KD + kk * 256 + c] = f2h_bits(w[i]);
}

// ---------------- Kernel 2b: x NCHW f32 -> xt NHWC f16 ----------------
__global__ __launch_bounds__(256) void xpose_kernel(const float* __restrict__ x,
                                                    u16* __restrict__ xt)
{
  __shared__ float t[64][65];
  int ptile = blockIdx.x;   // 64-pixel tile within image (0..63)
  int ctile = blockIdx.y;   // 64-channel tile (0..3)
  int b     = blockIdx.z;
  int tid = threadIdx.x;
  const float* xb = x + (size_t)b * CIN * 4096 + (size_t)ctile * 64 * 4096 + ptile * 64;
#pragma unroll
  for (int i = 0; i < 16; ++i) {
    int c = i * 4 + (tid >> 6), p = tid & 63;
    t[c][p] = xb[(size_t)c * 4096 + p];
  }
  __syncthreads();
  u16* xo = xt + ((size_t)b * 4096 + ptile * 64) * 256 + ctile * 64;
#pragma unroll
  for (int i = 0; i < 16; ++i) {
    int p = i * 4 + (tid >> 6), c = tid & 63;
    xo[(size_t)p * 256 + c] = f2h_bits(t[c][p]);
  }
}

// ---------------- Kernel 4: FUSED im2col+GEMM, 256cout x 128px, K-split x2 ----------------
// Grid 256 = 2 blocks/CU -> 4 waves/SIMD (the occupancy cell untested with a
// fat-M tile). 8 waves 4Mx2N, wave = 64cout x 64px: 16 MFMA vs 8 ds_read_b128
// per step. K=1152, 36 steps of 32. Triple-buf A + dbuf B (64KB LDS).
// Schedule = R9's proven single-barrier counted-vmcnt loop:
//   SAMP(t+1)[4] -> STAGE_A(t+2)[2] -> frags+MFMA(t) -> vmcnt(2)
//   [drains S(t+1)+A(t+1), keeps A(t+2) in flight across barrier] ->
//   BLEND/ds_write B(t+1) -> lgkmcnt(0) -> s_barrier.
// Swizzle (proven): slot' = slot ^ (r&3) ^ ((r>>2)&3) on A gload SOURCE
// (linear dest), B ds_write slot, and frag reads.
__global__ __launch_bounds__(512, 4) void gemm_fused_kernel(
    const u16* __restrict__ A,     // wb f16 [COUT][KD]
    const u16* __restrict__ xt,    // NHWC f16 [B*4096][256]
    const float* __restrict__ rec, // [NPIX][32]
    const float* __restrict__ bias,
    float* __restrict__ out,       // h==0 dest (+bias)
    float* __restrict__ tmp)       // h==1 dest (raw)
{
  __shared__ __align__(16) u16 lA[3][256 * 32];   // 3 x 16 KB
  __shared__ __align__(16) u16 lB[2][128 * 32];   // 2 x 8 KB
  const int tid = threadIdx.x;
  const int ord = blockIdx.x;            // 0..255
  const int xcd = ord & 7, slot = ord >> 3;      // bijective XCD remap
  const int ptile = (slot >> 1) * 8 + xcd;       // 0..127
  const int h     = slot & 1;                    // K half
  const int m0  = ptile * 128;
  const int b_img = ptile >> 5;          // 32 ptiles per image
  const int cbase = h * 128;
  const int wave = tid >> 6, lane = tid & 63;
  const int wm = wave >> 1, wn = wave & 1;
  const int rl = lane & 15, kq = lane >> 4;
  const int sA = (kq ^ (rl & 3) ^ ((rl >> 2) & 3)) * 8;

  // A staging: thread covers rows (tid>>2) and (tid>>2)+128, 16B each
  const int rA  = tid >> 2;
  const int koA = ((tid & 3) ^ (rA & 3) ^ ((rA >> 2) & 3)) * 8;
  const u16* aRow0 = A + (size_t)rA * KD + koA;
  const u16* aRow1 = A + (size_t)(rA + 128) * KD + koA;

  // B sampling: thread -> (pixel px_t, 8 channels ch8 within current 32-chunk)
  const int px_t = tid >> 2;             // 0..127
  const int ch8  = (tid & 3) * 8;        // 0,8,16,24
  const int m_px = m0 + px_t;
  const int ho = (m_px & 4095) >> 6, wo = m_px & 63;
  const float* rp = rec + (size_t)m_px * 32;
  const u16* xb = xt + (size_t)b_img * 4096 * 256;
  // B LDS write: row px_t, logical 16B-slot (tid&3), XOR-swizzled
  const int swzp = (px_t & 3) ^ ((px_t >> 2) & 3);
  const int wAddr = px_t * 32 + (((tid & 3) ^ swzp) * 8);

  u32 cOff[4];   // corner row element-offsets into xb
  h2  wh[4];     // corner weights broadcast as half2 (incl. mask)

  // step t: kk = t>>2, chunk col = kk*256 + cbase + (t&3)*32
#define KCOL(t_) (((t_) >> 2) * 256 + cbase + ((t_) & 3) * 32)

#define CALC_CORNERS(kk_) do {                                             \
    float dy = rp[(kk_) * 2], dx = rp[(kk_) * 2 + 1], msk = rp[18 + (kk_)];\
    float py  = (float)(ho - 1 + ((kk_) / 3)) + dy;                        \
    float pxf = (float)(wo - 1 + ((kk_) % 3)) + dx;                        \
    float fy = floorf(py), fx = floorf(pxf);                               \
    int y0 = (int)fy, x0 = (int)fx;                                        \
    float wy1 = py - fy, wy0 = 1.f - wy1;                                  \
    float wx1 = pxf - fx, wx0 = 1.f - wx1;                                 \
    _Pragma("unroll")                                                      \
    for (int cr = 0; cr < 4; ++cr) {                                       \
      int iy = y0 + (cr >> 1), ix = x0 + (cr & 1);                         \
      bool valid = (iy >= 0) & (iy < HH) & (ix >= 0) & (ix < WW);          \
      int iyc = min(max(iy, 0), HH - 1), ixc = min(max(ix, 0), WW - 1);    \
      cOff[cr] = (u32)(iyc * 64 + ixc) * 256;                              \
      float wy = (cr >> 1) ? wy1 : wy0;                                    \
      float wx = (cr & 1) ? wx1 : wx0;                                     \
      float wf = valid ? (wy * wx * msk) : 0.f;                            \
      _Float16 hw = (_Float16)wf;                                          \
      wh[cr] = (h2){hw, hw};                                               \
    }                                                                      \
  } while (0)

#define STAGE_A(k_, slot_) do {                                            \
    int k0_ = KCOL(k_);                                                    \
    gload_lds16(aRow0 + k0_, lA[slot_] + tid * 8);                         \
    gload_lds16(aRow1 + k0_, lA[slot_] + (tid + 512) * 8);                 \
  } while (0)

  // samples: per corner 1 x 16B (8 channels)
#define SAMP_LOAD(t_, va) do {                                             \
    int c0n_ = cbase + ((t_) & 3) * 32 + ch8;                              \
    _Pragma("unroll")                                                      \
    for (int cr = 0; cr < 4; ++cr)                                         \
      va[cr] = *(const uint4v*)(xb + cOff[cr] + c0n_);                     \
  } while (0)

#define BLEND_WRITE(bufi_, va) do {                                        \
    uint4v o0;                                                             \
    _Pragma("unroll")                                                      \
    for (int w_ = 0; w_ < 4; ++w_) {                                       \
      h2 s0_ = wh[0] * as_h2(va[0][w_]) + wh[1] * as_h2(va[1][w_]);        \
      s0_   += wh[2] * as_h2(va[2][w_]) + wh[3] * as_h2(va[3][w_]);        \
      o0[w_] = as_u32(s0_);                                                \
    }                                                                      \
    *(uint4v*)&lB[bufi_][wAddr] = o0;                                      \
  } while (0)

  float4v acc[4][4];
#pragma unroll
  for (int m = 0; m < 4; ++m)
#pragma unroll
    for (int n = 0; n < 4; ++n) acc[m][n] = float4v{0.f, 0.f, 0.f, 0.f};

  // ---- prologue: SAMP(0)[4] -> A(0)[2] -> A(1)[2]; vmcnt(2) keeps A(1) ----
  {
    CALC_CORNERS(0);
    uint4v va[4];
    SAMP_LOAD(0, va);
    STAGE_A(0, 0);
    STAGE_A(1, 1);
    asm volatile("s_waitcnt vmcnt(2)" ::: "memory");
    BLEND_WRITE(0, va);
    asm volatile("s_waitcnt lgkmcnt(0)" ::: "memory");
    __builtin_amdgcn_s_barrier();
  }

  for (int it = 0; it < 3; ++it) {
#pragma unroll
    for (int u = 0; u < 12; ++u) {
      const int t = it * 12 + u;
      const int tn  = (t + 1 == NSTEP) ? 0 : t + 1;               // sample idx
      const int tn2 = (t + 2 >= NSTEP) ? (t + 2 - NSTEP) : t + 2; // DMA idx
      // sample step t+1 (issued first: oldest VMEM after A(t+1))
      if ((tn & 3) == 0) CALC_CORNERS(tn >> 2);
      uint4v va[4];
      SAMP_LOAD(tn, va);
      // DMA step t+2 (newest; survives this step's vmcnt(2))
      STAGE_A(tn2, (u + 2) % 3);
      // frags + MFMA on step t
      h8 af[4], bf[4];
#pragma unroll
      for (int m = 0; m < 4; ++m)
        af[m] = *(const h8*)&lA[u % 3][(wm * 64 + m * 16 + rl) * 32 + sA];
#pragma unroll
      for (int n = 0; n < 4; ++n)
        bf[n] = *(const h8*)&lB[u & 1][(wn * 64 + n * 16 + rl) * 32 + sA];
#pragma unroll
      for (int m = 0; m < 4; ++m)
#pragma unroll
        for (int n = 0; n < 4; ++n)
          acc[m][n] = __builtin_amdgcn_mfma_f32_16x16x32_f16(af[m], bf[n], acc[m][n], 0, 0, 0);
      // S(t+1)+A(t+1) landed; A(t+2) stays in flight across the barrier
      asm volatile("s_waitcnt vmcnt(2)" ::: "memory");
      BLEND_WRITE((u + 1) & 1, va);
      asm volatile("s_waitcnt lgkmcnt(0)" ::: "memory");
      __builtin_amdgcn_s_barrier();
    }
  }
#undef STAGE_A
#undef CALC_CORNERS
#undef SAMP_LOAD
#undef BLEND_WRITE
#undef KCOL

  const int p_base = (m0 & 4095) + wn * 64;
  float* db = (h ? tmp : out) + (size_t)b_img * COUT * 4096;
#pragma unroll
  for (int m = 0; m < 4; ++m) {
#pragma unroll
    for (int j = 0; j < 4; ++j) {
      int co = wm * 64 + m * 16 + kq * 4 + j;
      float bv = h ? 0.f : bias[co];
#pragma unroll
      for (int n = 0; n < 4; ++n) {
        int pp = p_base + n * 16 + rl;
        db[(size_t)co * 4096 + pp] = acc[m][n][j] + bv;
      }
    }
  }
}

// ---------------- Kernel 5: out += tmp ----------------
__global__ __launch_bounds__(256) void add_kernel(float* __restrict__ out,
                                                  const float* __restrict__ tmp)
{
  size_t i = ((size_t)blockIdx.x * 256 + threadIdx.x) * 4;
  float4v a = *(const float4v*)(out + i);
  float4v b = *(const float4v*)(tmp + i);
  a += b;
  *(float4v*)(out + i) = a;
}

extern "C" void kernel_launch(void* const* d_in, const int* in_sizes, int n_in,
                              void* d_out, int out_size, void* d_ws, size_t ws_size,
                              hipStream_t stream) {
  const float* x       = (const float*)d_in[0];
  const float* weight  = (const float*)d_in[1];
  const float* bias    = (const float*)d_in[2];
  const float* off_dw  = (const float*)d_in[3];
  const float* off_pw  = (const float*)d_in[4];
  const float* mask_dw = (const float*)d_in[5];
  const float* mask_pw = (const float*)d_in[6];

  // ws layout: rec 2MB @0 | wb 1.18MB @2,097,152 | xt 8.39MB @3,276,800 |
  //            part 33.5MB @11,665,408 (tmp 16.78MB aliases part lower half;
  //            part consumed by reduce before gemm writes tmp) => 45,219,840 B
  if (ws_size < 45219840ull) return;
  float* rec  = (float*)d_ws;
  u16*   wb   = (u16*)((char*)d_ws + 2097152);
  u16*   xt   = (u16*)((char*)d_ws + 3276800);
  float* part = (float*)((char*)d_ws + 11665408);
  float* tmp  = part;
  float* out  = (float*)d_out;

  wconv_kernel<<<dim3(2304), dim3(256), 0, stream>>>(weight, wb);
  offmask_part_kernel<<<dim3(NPIX / 256, SPLIT), dim3(256), 0, stream>>>(
      x, off_dw, off_pw, mask_dw, mask_pw, part);
  offmask_reduce_kernel<<<dim3(NPIX * 32 / 256), dim3(256), 0, stream>>>(part, rec);
  xpose_kernel<<<dim3(64, 4, 4), dim3(256), 0, stream>>>(x, xt);
  gemm_fused_kernel<<<dim3(256), dim3(512), 0, stream>>>(wb, xt, rec, bias, out, tmp);
  add_kernel<<<dim3(COUT * NPIX / 4 / 256), dim3(256), 0, stream>>>(out, tmp);
}

// Round 14
// 92.885 us; speedup vs baseline: 1.3546x; 1.3546x over previous
//
#include <hip/hip_runtime.h>

#define CIN   256
#define COUT  256
#define HH    64
#define WW    64
#define KD    2304         // CIN * 9
#define NPIX  16384        // B * HO * WO
#define SPLIT 16
#define CPS   (CIN / SPLIT)
#define NSTEP 18           // K per quarter = 576 = 18 x 32

typedef __attribute__((ext_vector_type(4))) float  float4v;
typedef __attribute__((ext_vector_type(4))) unsigned int uint4v;
typedef _Float16 h2 __attribute__((ext_vector_type(2)));
typedef _Float16 h8 __attribute__((ext_vector_type(8)));
typedef unsigned int u32;
typedef unsigned short u16;

__device__ __forceinline__ h2 as_h2(u32 v) { union { u32 u; h2 h; } x; x.u = v; return x.h; }
__device__ __forceinline__ u32 as_u32(h2 h) { union { u32 u; h2 h; } x; x.h = h; return x.u; }
__device__ __forceinline__ u16 f2h_bits(float f) { _Float16 h = (_Float16)f; return *(u16*)&h; }
__device__ __forceinline__ float h2f(u16 b) { _Float16 h = *(_Float16*)&b; return (float)h; }
__device__ __forceinline__ u32 packh2(float a, float b) {
  h2 h; h[0] = (_Float16)a; h[1] = (_Float16)b; return as_u32(h);
}

__device__ __forceinline__ void gload_lds16(const void* g, void* l) {
  __builtin_amdgcn_global_load_lds((const __attribute__((address_space(1))) u32*)g,
                                   (__attribute__((address_space(3))) u32*)l, 16, 0, 0);
}

// ---------------- Kernel 1a: offset/mask partials (f16-packed), split x16 ----------------
// part2[s][m][16] u32: u32 k packs (acc[2k], acc[2k+1]) as h2; k=13 packs (acc[26], 0).
__global__ __launch_bounds__(256) void offmask_part_kernel(
    const float* __restrict__ x,
    const float* __restrict__ off_dw, const float* __restrict__ off_pw,
    const float* __restrict__ mask_dw, const float* __restrict__ mask_pw,
    u32* __restrict__ part2)
{
  int m = blockIdx.x * 256 + threadIdx.x;   // pixel id
  int s = blockIdx.y;                        // channel split
  int b = m >> 12, pix = m & 4095;
  int ho = pix >> 6, wo = pix & 63;
  const float* xb = x + (size_t)b * CIN * 4096;

  float acc[27];
#pragma unroll
  for (int j = 0; j < 27; ++j) acc[j] = 0.f;

  int c0 = s * CPS;
  for (int ci = 0; ci < CPS; ++ci) {
    int c = c0 + ci;
    const float* xc = xb + (size_t)c * 4096;
    float d_off = 0.f, d_msk = 0.f;
#pragma unroll
    for (int t = 0; t < 9; ++t) {
      int gy = ho + t / 3 - 1, gx = wo + t % 3 - 1;
      bool ok = (gy >= 0) & (gy < HH) & (gx >= 0) & (gx < WW);
      float v = ok ? xc[gy * 64 + gx] : 0.f;
      d_off += v * off_dw[c * 9 + t];
      d_msk += v * mask_dw[c * 9 + t];
    }
#pragma unroll
    for (int j = 0; j < 18; ++j) acc[j] += d_off * off_pw[j * 256 + c];
#pragma unroll
    for (int j = 0; j < 9; ++j) acc[18 + j] += d_msk * mask_pw[j * 256 + c];
  }
  uint4v o[4];
#pragma unroll
  for (int k = 0; k < 13; ++k) o[k >> 2][k & 3] = packh2(acc[2 * k], acc[2 * k + 1]);
  o[3][1] = packh2(acc[26], 0.f);
  o[3][2] = 0; o[3][3] = 0;
  uint4v* pp = (uint4v*)(part2 + ((size_t)s * NPIX + m) * 16);
#pragma unroll
  for (int q = 0; q < 4; ++q) pp[q] = o[q];
}

// ---------------- Kernel 1b: reduce f16 partials -> rec f32 (sigmoid on mask) ----------------
__global__ __launch_bounds__(256) void offmask_reduce_kernel(
    const u32* __restrict__ part2, float* __restrict__ rec)
{
  int i = blockIdx.x * 256 + threadIdx.x;   // over NPIX*16
  int m = i >> 4, k = i & 15;
  int j0 = 2 * k, j1 = 2 * k + 1;
  if (j0 >= 27) { rec[(size_t)m * 32 + j0] = 0.f; rec[(size_t)m * 32 + j1] = 0.f; return; }
  float s0 = 0.f, s1 = 0.f;
#pragma unroll
  for (int s = 0; s < SPLIT; ++s) {
    h2 v = as_h2(part2[((size_t)s * NPIX + m) * 16 + k]);
    s0 += (float)v[0]; s1 += (float)v[1];
  }
  rec[(size_t)m * 32 + j0] = (j0 < 18) ? s0 : 2.f / (1.f + __expf(-s0));
  rec[(size_t)m * 32 + j1] = (j1 < 18) ? s1 : ((j1 < 27) ? 2.f / (1.f + __expf(-s1)) : 0.f);
}

// ---------------- Kernel 2: weight f32 (co,c,ki,kj) -> f16 [co][kk*256 + c] ----------------
__global__ __launch_bounds__(256) void wconv_kernel(const float* __restrict__ w,
                                                    u16* __restrict__ wb)
{
  int i = blockIdx.x * 256 + threadIdx.x;     // over COUT*KD
  int co = i / KD, rem = i - co * KD;
  int c = rem / 9, kk = rem - c * 9;
  wb[co * KD + kk * 256 + c] = f2h_bits(w[i]);
}

// ---------------- Kernel 2b: x NCHW f32 -> xt NHWC f16 ----------------
__global__ __launch_bounds__(256) void xpose_kernel(const float* __restrict__ x,
                                                    u16* __restrict__ xt)
{
  __shared__ float t[64][65];
  int ptile = blockIdx.x;
  int ctile = blockIdx.y;
  int b     = blockIdx.z;
  int tid = threadIdx.x;
  const float* xb = x + (size_t)b * CIN * 4096 + (size_t)ctile * 64 * 4096 + ptile * 64;
#pragma unroll
  for (int i = 0; i < 16; ++i) {
    int c = i * 4 + (tid >> 6), p = tid & 63;
    t[c][p] = xb[(size_t)c * 4096 + p];
  }
  __syncthreads();
  u16* xo = xt + ((size_t)b * 4096 + ptile * 64) * 256 + ctile * 64;
#pragma unroll
  for (int i = 0; i < 16; ++i) {
    int p = i * 4 + (tid >> 6), c = tid & 63;
    xo[(size_t)p * 256 + c] = f2h_bits(t[c][p]);
  }
}

// ---------------- Kernel 4: FUSED im2col+GEMM, FAT TILE (R9/R11 core verbatim) ----------------
// Only change vs R11: epilogue writes f16 partial tile to tmp4[h] (no bias);
// add_kernel folds the 4 quarters + bias. WRITE traffic 66.5 -> 33.5 MB.
__global__ __launch_bounds__(512, 2) void gemm_fused_kernel(
    const u16* __restrict__ A,     // wb f16 [COUT][KD]
    const u16* __restrict__ xt,    // NHWC f16 [B*4096][256]
    const float* __restrict__ rec, // [NPIX][32]
    u16* __restrict__ tmp4)        // [4][B][COUT][4096] f16 partials
{
  __shared__ __align__(16) u16 lA[3][256 * 32];   // 3 x 16 KB
  __shared__ __align__(16) u16 lB[2][256 * 32];   // 2 x 16 KB
  const int tid = threadIdx.x;
  const int ord = blockIdx.x;            // 0..255
  const int xcd = ord & 7, slot = ord >> 3;
  const int ptile = (slot >> 2) * 8 + xcd;   // 0..63 (bijective remap)
  const int h     = slot & 3;                // K quarter
  const int m0  = ptile * 256;
  const int b_img = ptile >> 4;
  const int cbase = h * 64;
  const int wave = tid >> 6, lane = tid & 63;
  const int wm = wave >> 1, wn = wave & 1;
  const int rl = lane & 15, kq = lane >> 4;
  const int sA = (kq ^ (rl & 3) ^ ((rl >> 2) & 3)) * 8;

  const int rA  = tid >> 2;
  const int koA = ((tid & 3) ^ (rA & 3) ^ ((rA >> 2) & 3)) * 8;
  const u16* aRow0 = A + (size_t)rA * KD + koA;
  const u16* aRow1 = A + (size_t)(rA + 128) * KD + koA;

  const int px_t = tid >> 1;             // 0..255
  const int chh  = (tid & 1) * 16;       // 0 or 16
  const int m_px = m0 + px_t;
  const int ho = (m_px & 4095) >> 6, wo = m_px & 63;
  const float* rp = rec + (size_t)m_px * 32;
  const u16* xb = xt + (size_t)b_img * 4096 * 256;
  const int swzp = (px_t & 3) ^ ((px_t >> 2) & 3);
  const int wAddr0 = px_t * 32 + ((((tid & 1) * 2)     ^ swzp) * 8);
  const int wAddr1 = px_t * 32 + ((((tid & 1) * 2 + 1) ^ swzp) * 8);

  u32 cOff[4];
  h2  wh[4];

#define KCOL(t_) (((t_) >> 1) * 256 + cbase + ((t_) & 1) * 32)

#define CALC_CORNERS(kk_) do {                                             \
    float dy = rp[(kk_) * 2], dx = rp[(kk_) * 2 + 1], msk = rp[18 + (kk_)];\
    float py  = (float)(ho - 1 + ((kk_) / 3)) + dy;                        \
    float pxf = (float)(wo - 1 + ((kk_) % 3)) + dx;                        \
    float fy = floorf(py), fx = floorf(pxf);                               \
    int y0 = (int)fy, x0 = (int)fx;                                        \
    float wy1 = py - fy, wy0 = 1.f - wy1;                                  \
    float wx1 = pxf - fx, wx0 = 1.f - wx1;                                 \
    _Pragma("unroll")                                                      \
    for (int cr = 0; cr < 4; ++cr) {                                       \
      int iy = y0 + (cr >> 1), ix = x0 + (cr & 1);                         \
      bool valid = (iy >= 0) & (iy < HH) & (ix >= 0) & (ix < WW);          \
      int iyc = min(max(iy, 0), HH - 1), ixc = min(max(ix, 0), WW - 1);    \
      cOff[cr] = (u32)(iyc * 64 + ixc) * 256;                              \
      float wy = (cr >> 1) ? wy1 : wy0;                                    \
      float wx = (cr & 1) ? wx1 : wx0;                                     \
      float wf = valid ? (wy * wx * msk) : 0.f;                            \
      _Float16 hw = (_Float16)wf;                                          \
      wh[cr] = (h2){hw, hw};                                               \
    }                                                                      \
  } while (0)

#define STAGE_A(k_, slot_) do {                                            \
    int k0_ = KCOL(k_);                                                    \
    gload_lds16(aRow0 + k0_, lA[slot_] + tid * 8);                         \
    gload_lds16(aRow1 + k0_, lA[slot_] + (tid + 512) * 8);                 \
  } while (0)

#define SAMP_LOAD(t_, va, vb) do {                                         \
    int c0n_ = cbase + ((t_) & 1) * 32 + chh;                              \
    _Pragma("unroll")                                                      \
    for (int cr = 0; cr < 4; ++cr) {                                       \
      va[cr] = *(const uint4v*)(xb + cOff[cr] + c0n_);                     \
      vb[cr] = *(const uint4v*)(xb + cOff[cr] + c0n_ + 8);                 \
    }                                                                      \
  } while (0)

#define BLEND_WRITE(bufi_, va, vb) do {                                    \
    uint4v o0, o1;                                                         \
    _Pragma("unroll")                                                      \
    for (int w_ = 0; w_ < 4; ++w_) {                                       \
      h2 s0_ = wh[0] * as_h2(va[0][w_]) + wh[1] * as_h2(va[1][w_]);        \
      s0_   += wh[2] * as_h2(va[2][w_]) + wh[3] * as_h2(va[3][w_]);        \
      h2 s1_ = wh[0] * as_h2(vb[0][w_]) + wh[1] * as_h2(vb[1][w_]);        \
      s1_   += wh[2] * as_h2(vb[2][w_]) + wh[3] * as_h2(vb[3][w_]);        \
      o0[w_] = as_u32(s0_); o1[w_] = as_u32(s1_);                          \
    }                                                                      \
    *(uint4v*)&lB[bufi_][wAddr0] = o0;                                     \
    *(uint4v*)&lB[bufi_][wAddr1] = o1;                                     \
  } while (0)

  float4v acc[4][8];
#pragma unroll
  for (int m = 0; m < 4; ++m)
#pragma unroll
    for (int n = 0; n < 8; ++n) acc[m][n] = float4v{0.f, 0.f, 0.f, 0.f};

  // ---- prologue ----
  {
    CALC_CORNERS(0);
    uint4v va[4], vb[4];
    SAMP_LOAD(0, va, vb);
    STAGE_A(0, 0);
    STAGE_A(1, 1);
    asm volatile("s_waitcnt vmcnt(2)" ::: "memory");
    BLEND_WRITE(0, va, vb);
    asm volatile("s_waitcnt lgkmcnt(0)" ::: "memory");
    __builtin_amdgcn_s_barrier();
  }

  for (int it = 0; it < 3; ++it) {
#pragma unroll
    for (int u = 0; u < 6; ++u) {
      const int t = it * 6 + u;
      const int tn  = (t + 1 == NSTEP) ? 0 : t + 1;
      const int tn2 = (t + 2 >= NSTEP) ? (t + 2 - NSTEP) : t + 2;
      if ((tn & 1) == 0) CALC_CORNERS(tn >> 1);
      uint4v va[4], vb[4];
      SAMP_LOAD(tn, va, vb);
      STAGE_A(tn2, (u + 2) % 3);
      h8 af[4], bf[8];
#pragma unroll
      for (int m = 0; m < 4; ++m)
        af[m] = *(const h8*)&lA[u % 3][(wm * 64 + m * 16 + rl) * 32 + sA];
#pragma unroll
      for (int n = 0; n < 8; ++n)
        bf[n] = *(const h8*)&lB[u & 1][(wn * 128 + n * 16 + rl) * 32 + sA];
#pragma unroll
      for (int m = 0; m < 4; ++m)
#pragma unroll
        for (int n = 0; n < 8; ++n)
          acc[m][n] = __builtin_amdgcn_mfma_f32_16x16x32_f16(af[m], bf[n], acc[m][n], 0, 0, 0);
      asm volatile("s_waitcnt vmcnt(2)" ::: "memory");
      BLEND_WRITE((u + 1) & 1, va, vb);
      asm volatile("s_waitcnt lgkmcnt(0)" ::: "memory");
      __builtin_amdgcn_s_barrier();
    }
  }
#undef STAGE_A
#undef CALC_CORNERS
#undef SAMP_LOAD
#undef BLEND_WRITE
#undef KCOL

  const int p_base = (m0 & 4095) + wn * 128;
  u16* db = tmp4 + (size_t)h * COUT * NPIX + (size_t)b_img * COUT * 4096;
#pragma unroll
  for (int m = 0; m < 4; ++m) {
#pragma unroll
    for (int j = 0; j < 4; ++j) {
      int co = wm * 64 + m * 16 + kq * 4 + j;
#pragma unroll
      for (int n = 0; n < 8; ++n) {
        int pp = p_base + n * 16 + rl;
        db[(size_t)co * 4096 + pp] = f2h_bits(acc[m][n][j]);
      }
    }
  }
}

// ---------------- Kernel 5: out = bias + sum of 4 f16 quarter-tiles ----------------
__global__ __launch_bounds__(256) void add_kernel(const u16* __restrict__ tmp4,
                                                  const float* __restrict__ bias,
                                                  float* __restrict__ out)
{
  size_t i = ((size_t)blockIdx.x * 256 + threadIdx.x) * 8;  // over COUT*NPIX
  int co = (int)((i >> 12) & 255);
  float bv = bias[co];
  uint4v v0 = *(const uint4v*)(tmp4 + i);
  uint4v v1 = *(const uint4v*)(tmp4 + (size_t)COUT * NPIX + i);
  uint4v v2 = *(const uint4v*)(tmp4 + (size_t)2 * COUT * NPIX + i);
  uint4v v3 = *(const uint4v*)(tmp4 + (size_t)3 * COUT * NPIX + i);
  float4v oA, oB;
#pragma unroll
  for (int w = 0; w < 4; ++w) {
    h2 a = as_h2(v0[w]), b = as_h2(v1[w]), c = as_h2(v2[w]), d = as_h2(v3[w]);
    float lo = (float)a[0] + (float)b[0] + (float)c[0] + (float)d[0] + bv;
    float hi = (float)a[1] + (float)b[1] + (float)c[1] + (float)d[1] + bv;
    if (w < 2) { oA[w * 2] = lo; oA[w * 2 + 1] = hi; }
    else       { oB[(w - 2) * 2] = lo; oB[(w - 2) * 2 + 1] = hi; }
  }
  *(float4v*)(out + i) = oA;
  *(float4v*)(out + i + 4) = oB;
}

extern "C" void kernel_launch(void* const* d_in, const int* in_sizes, int n_in,
                              void* d_out, int out_size, void* d_ws, size_t ws_size,
                              hipStream_t stream) {
  const float* x       = (const float*)d_in[0];
  const float* weight  = (const float*)d_in[1];
  const float* bias    = (const float*)d_in[2];
  const float* off_dw  = (const float*)d_in[3];
  const float* off_pw  = (const float*)d_in[4];
  const float* mask_dw = (const float*)d_in[5];
  const float* mask_pw = (const float*)d_in[6];

  // ws layout: rec 2MB @0 | wb 1.18MB @2,097,152 | xt 8.39MB @3,276,800 |
  //            @11,665,408: part2 16.78MB (f16 partials, consumed by reduce)
  //            then tmp4 33.55MB aliases the same region (written by gemm
  //            AFTER reduce ran). total = 45,219,840 B
  if (ws_size < 45219840ull) return;
  float* rec   = (float*)d_ws;
  u16*   wb    = (u16*)((char*)d_ws + 2097152);
  u16*   xt    = (u16*)((char*)d_ws + 3276800);
  u32*   part2 = (u32*)((char*)d_ws + 11665408);
  u16*   tmp4  = (u16*)((char*)d_ws + 11665408);
  float* out   = (float*)d_out;

  wconv_kernel<<<dim3(2304), dim3(256), 0, stream>>>(weight, wb);
  offmask_part_kernel<<<dim3(NPIX / 256, SPLIT), dim3(256), 0, stream>>>(
      x, off_dw, off_pw, mask_dw, mask_pw, part2);
  offmask_reduce_kernel<<<dim3(NPIX * 16 / 256), dim3(256), 0, stream>>>(part2, rec);
  xpose_kernel<<<dim3(64, 4, 4), dim3(256), 0, stream>>>(x, xt);
  gemm_fused_kernel<<<dim3(256), dim3(512), 0, stream>>>(wb, xt, rec, tmp4);
  add_kernel<<<dim3(COUT * NPIX / 8 / 256), dim3(256), 0, stream>>>(tmp4, bias, out);
}